// Round 7
// baseline (49.222 us; speedup 1.0000x reference)
//
#include <hip/hip_runtime.h>
#include <hip/hip_bf16.h>

// Fused MPNN layer, B=256, N=81, H=128, E=1620 — MFMA bf16.
//   P = X @ Wm1[:H],  Q' = X @ Wm1[H:] + bm1
//   Hsum[t] = sum_{e: tgt=t} relu(P[src_e] + Q'[t])
//   Folded:  agg@Wu1b = (Hsum@Wc)*inv_deg + 1[deg>0]*bc,  Wc=Wm2@Wu1b, bc=bm2@Wu1b
//   h2 = relu(X@Wu1t + (Hsum@Wc)*inv + s*bc + bu1)
//   x  = X + h2 @ Wu2 + bu2 ;  out = LayerNorm(x)*gamma + beta
// Setup (grid 13 x 1024): blocks 0-7 pack {Wm1t,Wm1b,Wu1t,Wu2}; block 8 builds
//   deterministic CSR via per-chunk ballot match-masks; blocks 9-12 Wc + bc.
// Main (grid 256, 1024 thr = 16 waves): whole layer per batch in LDS.
//   r7: 6-way interleaved agg, unrolled LN, GEMM-A B-frag preload.

#define NN 81
#define HH 128
#define EE 1620
#define NCHK 26                         // ceil(EE/64)
#define MPAD 96
#define WB_BYTES 196608                 // 6 * 16384 ushorts (slot4 unused)
#define OFFS_OFF (WB_BYTES)             // int offs[82]
#define CSR_OFF  (OFFS_OFF + 82 * 4)    // int csr[1620]
#define BC_OFF   (CSR_OFF + EE * 4)     // float bc[128]
#define WS_NEED  (BC_OFF + HH * 4)

typedef __attribute__((ext_vector_type(8))) short bf16x8;
typedef __attribute__((ext_vector_type(8))) unsigned short ushort8v;
typedef __attribute__((ext_vector_type(4))) float f32x4;

__device__ __forceinline__ unsigned short f2b(float f) {
  union { float f; unsigned u; } v; v.f = f;
  unsigned r = v.u + 0x7fffu + ((v.u >> 16) & 1u);
  return (unsigned short)(r >> 16);
}
__device__ __forceinline__ float b2f(unsigned short h) {
  union { unsigned u; float f; } v; v.u = ((unsigned)h) << 16;
  return v.f;
}
__device__ __forceinline__ unsigned f2b2(float x, float y) {  // packed RNE pair
  float2 f; f.x = x; f.y = y;
  union { __hip_bfloat162 h; unsigned u; } v;
  v.h = __float22bfloat162_rn(f);
  return v.u;
}
__device__ __forceinline__ unsigned swzu(int r, int laneb) {
  return ((unsigned)(r * 256 + laneb)) ^ ((unsigned)((r & 7) << 4));
}

// ---------------- setup kernel ------------------------------------------------
__global__ __launch_bounds__(1024)
void setup_kernel(const float* __restrict__ Wm1, const float* __restrict__ Wm2,
                  const float* __restrict__ Wu1, const float* __restrict__ Wu2,
                  const float* __restrict__ bm2, const int* __restrict__ eidx,
                  char* __restrict__ ws) {
  __shared__ __align__(16) char arena[81920];
  const int tid = threadIdx.x;

  if (blockIdx.x < 8) {
    // ---- pack 4 source mats: 8*1024 threads = 4 mats * 8 nt * 4 ks * 64 ----
    const int gid = blockIdx.x * 1024 + tid;
    const int lane = gid & 63;
    const int t = gid >> 6;                 // mat*32 + nt*4 + ks  (0..127)
    const int ks = t & 3, nt = (t >> 2) & 7, mat = t >> 5;
    const float* src;
    int slot;
    if (mat == 0)      { src = Wm1;           slot = 0; }
    else if (mat == 1) { src = Wm1 + HH * HH; slot = 1; }
    else if (mat == 2) { src = Wu1;           slot = 3; }
    else               { src = Wu2;           slot = 5; }
    const int c = nt * 16 + (lane & 15);
    const int k0 = ks * 32 + (lane >> 4) * 8;
    bf16x8 pv;
#pragma unroll
    for (int j = 0; j < 8; ++j) pv[j] = (short)f2b(src[(k0 + j) * HH + c]);
    *(bf16x8*)((unsigned short*)ws + (size_t)slot * 16384 + (((nt * 4 + ks) * 64) + lane) * 8) = pv;
    return;
  }

  if (blockIdx.x == 8) {
    // ---- deterministic CSR via ballot match-masks (stable counting sort) ----
    int* srcE  = (int*)arena;            // EE
    int* tgtE  = srcE + EE;              // EE
    int* rankS = tgtE + EE;              // EE
    int* cntC  = rankS + EE;             // NCHK*NN
    int* tot   = cntC + NCHK * NN;       // NN
    int* scanS = tot + NN;               // 128
    int* wsumS = scanS + 128;            // 2
    int* offsS = wsumS + 2;              // NN+1
    for (int i = tid; i < NCHK * NN; i += 1024) cntC[i] = 0;
    for (int i = tid; i < 2 * EE; i += 1024) srcE[i] = eidx[i];
    __syncthreads();
    const int lane = tid & 63, wv = tid >> 6;
    for (int c = wv; c < NCHK; c += 16) {
      const int e = c * 64 + lane;
      const bool ok = (e < EE);
      const int t = ok ? tgtE[e] : -1;
      unsigned long long mymask = 0;
#pragma unroll
      for (int i = 0; i < 64; ++i) {
        const int ti = __shfl(t, i);
        const unsigned long long bal = __ballot(t == ti);
        if (i == lane) mymask = bal;
      }
      if (ok) {
        const int rank = __popcll(mymask & ((1ull << lane) - 1ull));
        rankS[e] = rank;
        if (rank == 0) cntC[c * NN + t] = __popcll(mymask);
      }
    }
    __syncthreads();
    if (tid < NN) {
      int s = 0;
#pragma unroll
      for (int c = 0; c < NCHK; ++c) s += cntC[c * NN + tid];
      tot[tid] = s;
    }
    __syncthreads();
    if (tid < 128) {
      const int l = tid & 63, w = tid >> 6;
      int inc = (tid < NN) ? tot[tid] : 0;
#pragma unroll
      for (int d = 1; d < 64; d <<= 1) {
        int u = __shfl_up(inc, d);
        if (l >= d) inc += u;
      }
      scanS[tid] = inc;
      if (l == 63) wsumS[w] = inc;
    }
    __syncthreads();
    if (tid < 128) {
      const int w = tid >> 6;
      const int inc = scanS[tid] + (w ? wsumS[0] : 0);
      if (tid < NN) offsS[tid] = inc - tot[tid];
      if (tid == NN - 1) offsS[NN] = inc;
    }
    __syncthreads();
    if (tid < NN) {  // chunk bases
      int run = offsS[tid];
#pragma unroll
      for (int c = 0; c < NCHK; ++c) {
        const int tmp = cntC[c * NN + tid];
        cntC[c * NN + tid] = run;
        run += tmp;
      }
    }
    __syncthreads();
    int* wofs = (int*)(ws + OFFS_OFF);
    int* wcsr = (int*)(ws + CSR_OFF);
    for (int i = tid; i <= NN; i += 1024) wofs[i] = offsS[i];
    for (int e = tid; e < EE; e += 1024) {
      const int t = tgtE[e];
      wcsr[cntC[(e >> 6) * NN + t] + rankS[e]] = srcE[e];
    }
    return;
  }

  // ---- blocks 9-12: Wc = Wm2 @ Wu1b, rows [32*bs, 32*bs+32); pack slot 2 ----
  {
    const int bs = blockIdx.x - 9;      // = ks slice
    float* WuL = (float*)arena;         // [128][128]
    float* WmL = WuL + HH * HH;         // [32][128]
    const float* Wu1b = Wu1 + HH * HH;
    float4* WuL4 = (float4*)WuL;
    const float4* src4 = (const float4*)Wu1b;
    for (int i = tid; i < HH * HH / 4; i += 1024) WuL4[i] = src4[i];
    const float4* wm4 = (const float4*)(Wm2 + bs * 32 * HH);
    float4* WmL4 = (float4*)WmL;
    if (tid < 32 * HH / 4) WmL4[tid] = wm4[tid];
    __syncthreads();
    const int kk = tid >> 5;            // 0..31 local row
    const int k  = bs * 32 + kk;
    const int cg = tid & 31;            // float4 col group
    f32x4 acc = (f32x4)0.f;
    for (int j = 0; j < HH; ++j) {
      const float a = WmL[kk * HH + j];
      const float4 w = WuL4[j * 32 + cg];
      acc[0] += a * w.x; acc[1] += a * w.y; acc[2] += a * w.z; acc[3] += a * w.w;
    }
    unsigned short* dst = (unsigned short*)ws;
#pragma unroll
    for (int q = 0; q < 4; ++q) {
      const int c = cg * 4 + q;
      const int nt = c >> 4;
      const int l = (((k & 31) >> 3) << 4) | (c & 15);
      dst[(size_t)2 * 16384 + (((nt * 4 + bs) * 64) + l) * 8 + (k & 7)] = f2b(acc[q]);
    }
    if (bs == 0 && tid < HH) {
      float s = 0.f;
      for (int j = 0; j < HH; ++j) s += bm2[j] * WuL[j * HH + tid];
      ((float*)(ws + BC_OFF))[tid] = s;
    }
  }
}

// ---------------- MFMA tile GEMM helpers (per wave: 3 M-tiles x 1 N-tile) -----
__device__ __forceinline__ void gemm3x1(const unsigned short* Ab, const unsigned short* Wp,
                                        int lane, int mt0, int nt0, f32x4 acc[3]) {
  bf16x8 Bf[4];
#pragma unroll
  for (int ks = 0; ks < 4; ++ks)
    Bf[ks] = *(const bf16x8*)(Wp + ((nt0 * 4 + ks) * 64 + lane) * 8);
  const int rl = lane & 15;
  const int kb = (lane >> 4) * 16;
  const unsigned swz = (unsigned)((rl & 7) << 4);
#pragma unroll
  for (int ks = 0; ks < 4; ++ks)
#pragma unroll
    for (int mm = 0; mm < 3; ++mm) {
      const int r = (mt0 + mm) * 16 + rl;
      const unsigned byte = (unsigned)(r * 256) + (((unsigned)(ks * 64 + kb)) ^ swz);
      bf16x8 a = *(const bf16x8*)((const char*)Ab + byte);
      acc[mm] = __builtin_amdgcn_mfma_f32_16x16x32_bf16(a, Bf[ks], acc[mm], 0, 0, 0);
    }
}

// dual-B with PRELOADED B fragments (loads issued before the stage barrier)
__device__ __forceinline__ void gemm3x1x2_preB(const unsigned short* Ab,
                                               const bf16x8 B0[4], const bf16x8 B1[4],
                                               int lane, int mt0,
                                               f32x4 acc0[3], f32x4 acc1[3]) {
  const int rl = lane & 15;
  const int kb = (lane >> 4) * 16;
  const unsigned swz = (unsigned)((rl & 7) << 4);
#pragma unroll
  for (int ks = 0; ks < 4; ++ks)
#pragma unroll
    for (int mm = 0; mm < 3; ++mm) {
      const int r = (mt0 + mm) * 16 + rl;
      const unsigned byte = (unsigned)(r * 256) + (((unsigned)(ks * 64 + kb)) ^ swz);
      bf16x8 a = *(const bf16x8*)((const char*)Ab + byte);
      acc0[mm] = __builtin_amdgcn_mfma_f32_16x16x32_bf16(a, B0[ks], acc0[mm], 0, 0, 0);
      acc1[mm] = __builtin_amdgcn_mfma_f32_16x16x32_bf16(a, B1[ks], acc1[mm], 0, 0, 0);
    }
}

// dual-A, two B mats (T = Hsum@Wc, U = Xb@Wu1t share the K-loop)
__device__ __forceinline__ void gemm3x1_2A(const unsigned short* A0, const unsigned short* A1,
                                           const unsigned short* Wp0, const unsigned short* Wp1,
                                           int lane, int mt0, int nt0,
                                           f32x4 acc0[3], f32x4 acc1[3]) {
  bf16x8 B0[4], B1[4];
#pragma unroll
  for (int ks = 0; ks < 4; ++ks) {
    B0[ks] = *(const bf16x8*)(Wp0 + ((nt0 * 4 + ks) * 64 + lane) * 8);
    B1[ks] = *(const bf16x8*)(Wp1 + ((nt0 * 4 + ks) * 64 + lane) * 8);
  }
  const int rl = lane & 15;
  const int kb = (lane >> 4) * 16;
  const unsigned swz = (unsigned)((rl & 7) << 4);
#pragma unroll
  for (int ks = 0; ks < 4; ++ks)
#pragma unroll
    for (int mm = 0; mm < 3; ++mm) {
      const int r = (mt0 + mm) * 16 + rl;
      const unsigned byte = (unsigned)(r * 256) + (((unsigned)(ks * 64 + kb)) ^ swz);
      bf16x8 a0 = *(const bf16x8*)((const char*)A0 + byte);
      acc0[mm] = __builtin_amdgcn_mfma_f32_16x16x32_bf16(a0, B0[ks], acc0[mm], 0, 0, 0);
      bf16x8 a1 = *(const bf16x8*)((const char*)A1 + byte);
      acc1[mm] = __builtin_amdgcn_mfma_f32_16x16x32_bf16(a1, B1[ks], acc1[mm], 0, 0, 0);
    }
}

__global__ __launch_bounds__(1024, 4)
void mpnn_mfma5_kernel(const float* __restrict__ node,
                       const float* __restrict__ bm1,
                       const float* __restrict__ bu1, const float* __restrict__ bu2,
                       const float* __restrict__ gamma_, const float* __restrict__ beta_,
                       const char* __restrict__ ws,
                       float* __restrict__ out) {
  __shared__ float X[NN][HH];                 // fp32 for residual + LN
  __shared__ unsigned short Xb[MPAD * HH];    // swizzled bf16
  __shared__ unsigned short bufP[MPAD * HH];  // P -> h2
  __shared__ unsigned short bufQ[MPAD * HH];  // Q' -> Hsum
  __shared__ int   csrL[EE];
  __shared__ int   offsL[NN + 1];
  __shared__ float bias[6][HH];               // bm1,bc,bu1,bu2,gamma,beta

  const int tid  = threadIdx.x;
  const int lane = tid & 63;
  const int wave = tid >> 6;     // 0..15
  const int b    = blockIdx.x;

  const unsigned short* wpk = (const unsigned short*)ws;
  const int* wofs = (const int*)(ws + OFFS_OFF);
  const int* wcsr = (const int*)(ws + CSR_OFF);
  const float* wbc = (const float*)(ws + BC_OFF);

  // ---- wave tile map: 16 waves = 8 N-tiles x 2 M-halves (3 M-tiles each) ----
  const int nt0 = wave & 7;
  const int mt0 = 3 * (wave >> 3);
  const int erow = (lane >> 4) * 4;
  const int ecol = lane & 15;

  // ---- GEMM A B-frag preload (global, independent of LDS staging) ----
  bf16x8 BA0[4], BA1[4];
#pragma unroll
  for (int ks = 0; ks < 4; ++ks) {
    BA0[ks] = *(const bf16x8*)(wpk + ((nt0 * 4 + ks) * 64 + lane) * 8);
    BA1[ks] = *(const bf16x8*)(wpk + 16384 + ((nt0 * 4 + ks) * 64 + lane) * 8);
  }

  // ---- stage: 3 prefetched loads/thread, packed bf16 conversion ----
  {
    const float4* nf4 = (const float4*)(node + (size_t)b * NN * HH);
    const int i2 = tid + 2048;
    const bool has2 = (i2 < NN * HH / 4);     // NN*HH/4 = 2592
    float4 v0 = nf4[tid];
    float4 v1 = nf4[tid + 1024];
    float4 v2 = has2 ? nf4[i2] : make_float4(0.f, 0.f, 0.f, 0.f);
#pragma unroll
    for (int k = 0; k < 3; ++k) {
      const int i = tid + k * 1024;
      if (k == 2 && !has2) break;
      const float4 v = (k == 0) ? v0 : (k == 1) ? v1 : v2;
      const int r = i >> 5, c = (i & 31) * 4;
      *(float4*)&X[r][c] = v;
      unsigned pk0 = f2b2(v.x, v.y), pk1 = f2b2(v.z, v.w);
      uint2 pv; pv.x = pk0; pv.y = pk1;
      *(uint2*)((char*)Xb + swzu(r, c * 2)) = pv;
    }
    if (tid < (MPAD - NN) * 16) {   // zero pad rows 81..95
      const int r = NN + tid / 16, m = tid % 16;
      ushort8v z = {0,0,0,0,0,0,0,0};
      *(ushort8v*)((char*)Xb + swzu(r, m * 16)) = z;
    }
    for (int i = tid; i < EE; i += 1024) csrL[i] = wcsr[i];
    if (tid < NN + 1) offsL[tid] = wofs[tid];
    if (tid < HH) {
      bias[0][tid] = bm1[tid];  bias[1][tid] = wbc[tid];
      bias[2][tid] = bu1[tid];  bias[3][tid] = bu2[tid];
      bias[4][tid] = gamma_[tid]; bias[5][tid] = beta_[tid];
    }
  }
  __syncthreads();

  // ---- GEMM A: P = Xb@Wm1t -> bufP ; Q' = Xb@Wm1b + bm1 -> bufQ ----
  {
    f32x4 accP[3], accQ[3];
#pragma unroll
    for (int mm = 0; mm < 3; ++mm) { accP[mm] = (f32x4)0.f; accQ[mm] = (f32x4)0.f; }
    gemm3x1x2_preB(Xb, BA0, BA1, lane, mt0, accP, accQ);
#pragma unroll
    for (int mm = 0; mm < 3; ++mm)
#pragma unroll
      for (int rg = 0; rg < 4; ++rg) {
        const int R = (mt0 + mm) * 16 + erow + rg;
        const int C = nt0 * 16 + ecol;
        const unsigned byte = swzu(R, C * 2);
        const bool ok = (R < NN);
        *(unsigned short*)((char*)bufP + byte) = ok ? f2b(accP[mm][rg]) : (unsigned short)0;
        *(unsigned short*)((char*)bufQ + byte) = ok ? f2b(accQ[mm][rg] + bias[0][C]) : (unsigned short)0;
      }
  }
  __syncthreads();

  // ---- edge aggregation, 6-way interleaved: Hsum[t]=sum relu(P[s]+Q'[t]) ----
  {
    const int lb = lane * 4;
    int o0[6], dd[6];
    float q0[6], q1[6], h0[6], h1[6];
#pragma unroll
    for (int k = 0; k < 6; ++k) {
      int t = wave + 16 * k;
      const bool ok = (t < NN);
      t = ok ? t : 0;
      o0[k] = offsL[t];
      dd[k] = ok ? (offsL[t + 1] - o0[k]) : 0;
      const unsigned pq = *(const unsigned*)((const char*)bufQ + swzu(t, lb));
      q0[k] = b2f((unsigned short)(pq & 0xffff));
      q1[k] = b2f((unsigned short)(pq >> 16));
      h0[k] = 0.f; h1[k] = 0.f;
    }
    int dmax = 0;
#pragma unroll
    for (int k = 0; k < 6; ++k) dmax = max(dmax, dd[k]);
#pragma unroll 2
    for (int j = 0; j < dmax; ++j) {
#pragma unroll
      for (int k = 0; k < 6; ++k) {
        const int jj = (j < dd[k]) ? j : 0;     // clamped safe read
        const int s = csrL[o0[k] + jj];
        const unsigned pp = *(const unsigned*)((const char*)bufP + swzu(s, lb));
        const float m = (j < dd[k]) ? 1.f : 0.f;
        h0[k] += m * fmaxf(b2f((unsigned short)(pp & 0xffff)) + q0[k], 0.f);
        h1[k] += m * fmaxf(b2f((unsigned short)(pp >> 16))    + q1[k], 0.f);
      }
    }
#pragma unroll
    for (int k = 0; k < 6; ++k) {
      const int t = wave + 16 * k;
      if (t < NN) {
        const unsigned hv = (unsigned)f2b(h0[k]) | ((unsigned)f2b(h1[k]) << 16);
        *(unsigned*)((char*)bufQ + swzu(t, lb)) = hv;
      }
    }
  }
  __syncthreads();

  // ---- GEMM BC: T = Hsum@Wc ; U = Xb@Wu1t ;
  //      h2 = relu(U + T*inv_deg + s*bc + bu1) -> bufP ----
  {
    f32x4 accT[3], accU[3];
#pragma unroll
    for (int mm = 0; mm < 3; ++mm) { accT[mm] = (f32x4)0.f; accU[mm] = (f32x4)0.f; }
    gemm3x1_2A(bufQ, Xb, wpk + 2 * 16384, wpk + 3 * 16384, lane, mt0, nt0, accT, accU);
#pragma unroll
    for (int mm = 0; mm < 3; ++mm)
#pragma unroll
      for (int rg = 0; rg < 4; ++rg) {
        const int R = (mt0 + mm) * 16 + erow + rg;
        const int C = nt0 * 16 + ecol;
        float v = 0.f;
        if (R < NN) {
          const int dg = offsL[R + 1] - offsL[R];
          const float inv = (dg > 0) ? 1.f / (float)dg : 1.f;
          const float sf  = (dg > 0) ? 1.f : 0.f;
          v = fmaxf(accU[mm][rg] + accT[mm][rg] * inv + sf * bias[1][C] + bias[2][C], 0.f);
        }
        *(unsigned short*)((char*)bufP + swzu(R, C * 2)) = f2b(v);
      }
  }
  __syncthreads();

  // ---- GEMM D: x = X + h2@Wu2 + bu2 (in place into X fp32) ----
  {
    f32x4 acc[3];
#pragma unroll
    for (int mm = 0; mm < 3; ++mm) acc[mm] = (f32x4)0.f;
    gemm3x1(bufP, wpk + 5 * 16384, lane, mt0, nt0, acc);
#pragma unroll
    for (int mm = 0; mm < 3; ++mm)
#pragma unroll
      for (int rg = 0; rg < 4; ++rg) {
        const int R = (mt0 + mm) * 16 + erow + rg;
        const int C = nt0 * 16 + ecol;
        if (R < NN) X[R][C] += acc[mm][rg] + bias[3][C];
      }
  }
  __syncthreads();

  // ---- LayerNorm, 6-row unrolled/interleaved + store ----
  {
    float x0[6], x1[6], mu[6], rstd[6];
#pragma unroll
    for (int k = 0; k < 6; ++k) {
      const int r = wave + 16 * k;
      const int rr = (r < NN) ? r : 0;
      x0[k] = X[rr][lane]; x1[k] = X[rr][lane + 64];
    }
#pragma unroll
    for (int k = 0; k < 6; ++k) {
      float s = x0[k] + x1[k];
#pragma unroll
      for (int off = 32; off; off >>= 1) s += __shfl_xor(s, off);
      mu[k] = s * (1.f / 128.f);
    }
#pragma unroll
    for (int k = 0; k < 6; ++k) {
      const float d0 = x0[k] - mu[k], d1 = x1[k] - mu[k];
      float v = d0 * d0 + d1 * d1;
#pragma unroll
      for (int off = 32; off; off >>= 1) v += __shfl_xor(v, off);
      rstd[k] = rsqrtf(v * (1.f / 128.f) + 1e-5f);
    }
#pragma unroll
    for (int k = 0; k < 6; ++k) {
      const int r = wave + 16 * k;
      if (r < NN) {
        const float d0 = x0[k] - mu[k], d1 = x1[k] - mu[k];
        const size_t o = ((size_t)b * NN + r) * HH;
        out[o + lane]      = d0 * rstd[k] * bias[4][lane]      + bias[5][lane];
        out[o + lane + 64] = d1 * rstd[k] * bias[4][lane + 64] + bias[5][lane + 64];
      }
    }
  }
}

// ================= fp32 fallback (known-good, used only if ws too small) =====
__device__ __forceinline__ void gemm_acc_f32(const float (*A)[HH], const float* __restrict__ Wg,
                                             int c, int row0, int nr, float (&acc)[41]) {
  float w[8];
#pragma unroll
  for (int j = 0; j < 8; ++j) w[j] = Wg[j * HH + c];
  for (int k0 = 0; k0 < HH; k0 += 8) {
    float wn[8];
    if (k0 + 8 < HH) {
#pragma unroll
      for (int j = 0; j < 8; ++j) wn[j] = Wg[(k0 + 8 + j) * HH + c];
    }
#pragma unroll
    for (int i = 0; i < 41; ++i) {
      if (i < nr) {
        const float4 a0 = *(const float4*)&A[row0 + i][k0];
        const float4 a1 = *(const float4*)&A[row0 + i][k0 + 4];
        acc[i] += a0.x * w[0] + a0.y * w[1] + a0.z * w[2] + a0.w * w[3]
                + a1.x * w[4] + a1.y * w[5] + a1.z * w[6] + a1.w * w[7];
      }
    }
#pragma unroll
    for (int j = 0; j < 8; ++j) w[j] = wn[j];
  }
}

__global__ __launch_bounds__(256, 1)
void mpnn_fused_kernel(const float* __restrict__ node, const int* __restrict__ eidx,
                       const float* __restrict__ Wm1, const float* __restrict__ bm1,
                       const float* __restrict__ Wm2, const float* __restrict__ bm2,
                       const float* __restrict__ Wu1, const float* __restrict__ bu1,
                       const float* __restrict__ Wu2, const float* __restrict__ bu2,
                       const float* __restrict__ gamma_, const float* __restrict__ beta_,
                       float* __restrict__ out) {
  __shared__ float X[NN][HH];
  __shared__ float Pb[NN][HH];
  __shared__ float Qb[NN][HH];
  __shared__ int   edg[2 * EE];
  __shared__ int   csr[EE];
  __shared__ int   offs[NN + 1];
  __shared__ int   cnt3[3][NN];
  __shared__ int   base3[3][NN];
  __shared__ float biases[6][HH];

  const int tid  = threadIdx.x;
  const int lane = tid & 63;
  const int wave = tid >> 6;
  const int b    = blockIdx.x;

  {
    const float4* nf4 = (const float4*)(node + (size_t)b * NN * HH);
    float4* X4 = (float4*)&X[0][0];
    for (int i = tid; i < NN * HH / 4; i += 256) X4[i] = nf4[i];
    for (int i = tid; i < 2 * EE; i += 256) edg[i] = eidx[i];
    if (tid < HH) {
      biases[0][tid] = bm1[tid]; biases[1][tid] = bm2[tid];
      biases[2][tid] = bu1[tid]; biases[3][tid] = bu2[tid];
      biases[4][tid] = gamma_[tid]; biases[5][tid] = beta_[tid];
    }
  }
  __syncthreads();
  if (tid < 3 * NN) {
    const int t = tid % NN, ch = tid / NN;
    const int e0 = ch * 540, e1 = e0 + 540;
    int cnt = 0;
    for (int e = e0; e < e1; ++e) cnt += (edg[EE + e] == t);
    cnt3[ch][t] = cnt;
  }
  __syncthreads();
  if (tid == 0) {
    int run = 0;
    for (int t = 0; t < NN; ++t) {
      offs[t] = run;
      base3[0][t] = run;
      base3[1][t] = base3[0][t] + cnt3[0][t];
      base3[2][t] = base3[1][t] + cnt3[1][t];
      run = base3[2][t] + cnt3[2][t];
    }
    offs[NN] = run;
  }
  __syncthreads();
  if (tid < 3 * NN) {
    const int t = tid % NN, ch = tid / NN;
    const int e0 = ch * 540, e1 = e0 + 540;
    int pos = base3[ch][t];
    for (int e = e0; e < e1; ++e)
      if (edg[EE + e] == t) csr[pos++] = edg[e];
  }
  __syncthreads();

  const int c    = ((wave & 1) << 6) | lane;
  const int row0 = (wave >> 1) ? 41 : 0;
  const int nr   = (wave >> 1) ? 40 : 41;

  {
    float acc[41];
#pragma unroll
    for (int i = 0; i < 41; ++i) acc[i] = 0.f;
    gemm_acc_f32(X, Wm1, c, row0, nr, acc);
#pragma unroll
    for (int i = 0; i < 41; ++i) if (i < nr) Pb[row0 + i][c] = acc[i];
  }
  {
    float acc[41];
#pragma unroll
    for (int i = 0; i < 41; ++i) acc[i] = 0.f;
    gemm_acc_f32(X, Wm1 + HH * HH, c, row0, nr, acc);
#pragma unroll
    for (int i = 0; i < 41; ++i) if (i < nr) Qb[row0 + i][c] = acc[i];
  }
  __syncthreads();

  for (int t = wave; t < NN; t += 4) {
    const int o0 = offs[t], o1 = offs[t + 1];
    const float q0 = Qb[t][lane]      + biases[0][lane];
    const float q1 = Qb[t][lane + 64] + biases[0][lane + 64];
    float h0 = 0.f, h1 = 0.f;
    for (int e = o0; e < o1; ++e) {
      const int s = csr[e];
      h0 += fmaxf(Pb[s][lane]      + q0, 0.f);
      h1 += fmaxf(Pb[s][lane + 64] + q1, 0.f);
    }
    Qb[t][lane]      = h0;
    Qb[t][lane + 64] = h1;
  }
  __syncthreads();

  {
    float acc[41];
#pragma unroll
    for (int i = 0; i < 41; ++i) acc[i] = 0.f;
    gemm_acc_f32(Qb, Wm2, c, row0, nr, acc);
#pragma unroll
    for (int i = 0; i < 41; ++i) if (i < nr) {
      const int r = row0 + i;
      const float d = (float)(offs[r + 1] - offs[r]);
      Pb[r][c] = (acc[i] + d * biases[1][c]) * (1.f / fmaxf(d, 1.f));
    }
  }
  __syncthreads();

  {
    float acc[41];
#pragma unroll
    for (int i = 0; i < 41; ++i) acc[i] = 0.f;
    gemm_acc_f32(X,  Wu1,           c, row0, nr, acc);
    gemm_acc_f32(Pb, Wu1 + HH * HH, c, row0, nr, acc);
#pragma unroll
    for (int i = 0; i < 41; ++i) if (i < nr)
      Qb[row0 + i][c] = fmaxf(acc[i] + biases[2][c], 0.f);
  }
  __syncthreads();

  {
    float acc[41];
#pragma unroll
    for (int i = 0; i < 41; ++i) acc[i] = 0.f;
    gemm_acc_f32(Qb, Wu2, c, row0, nr, acc);
#pragma unroll
    for (int i = 0; i < 41; ++i) if (i < nr) {
      const int r = row0 + i;
      X[r][c] = X[r][c] + acc[i] + biases[3][c];
    }
  }
  __syncthreads();

  for (int r = wave; r < NN; r += 4) {
    const float x0 = X[r][lane], x1 = X[r][lane + 64];
    float s = x0 + x1;
#pragma unroll
    for (int off = 32; off; off >>= 1) s += __shfl_xor(s, off);
    const float mu = s * (1.f / 128.f);
    const float d0 = x0 - mu, d1 = x1 - mu;
    float v = d0 * d0 + d1 * d1;
#pragma unroll
    for (int off = 32; off; off >>= 1) v += __shfl_xor(v, off);
    const float rstd = rsqrtf(v * (1.f / 128.f) + 1e-5f);
    const size_t o = ((size_t)b * NN + r) * HH;
    out[o + lane]      = d0 * rstd * biases[4][lane]      + biases[5][lane];
    out[o + lane + 64] = d1 * rstd * biases[4][lane + 64] + biases[5][lane + 64];
  }
}

extern "C" void kernel_launch(void* const* d_in, const int* in_sizes, int n_in,
                              void* d_out, int out_size, void* d_ws, size_t ws_size,
                              hipStream_t stream) {
  (void)in_sizes; (void)n_in; (void)out_size;
  const float* node  = (const float*)d_in[0];
  const int*   eidx  = (const int*)  d_in[1];
  const float* Wm1   = (const float*)d_in[2];
  const float* bm1   = (const float*)d_in[3];
  const float* Wm2   = (const float*)d_in[4];
  const float* bm2   = (const float*)d_in[5];
  const float* Wu1   = (const float*)d_in[6];
  const float* bu1   = (const float*)d_in[7];
  const float* Wu2   = (const float*)d_in[8];
  const float* bu2   = (const float*)d_in[9];
  const float* gamma_= (const float*)d_in[10];
  const float* beta_ = (const float*)d_in[11];
  float* outp = (float*)d_out;

  if (ws_size >= (size_t)WS_NEED) {
    char* ws = (char*)d_ws;
    hipLaunchKernelGGL(setup_kernel, dim3(13), dim3(1024), 0, stream,
                       Wm1, Wm2, Wu1, Wu2, bm2, eidx, ws);
    hipLaunchKernelGGL(mpnn_mfma5_kernel, dim3(256), dim3(1024), 0, stream,
                       node, bm1, bu1, bu2, gamma_, beta_, ws, outp);
  } else {
    hipLaunchKernelGGL(mpnn_fused_kernel, dim3(256), dim3(256), 0, stream,
                       node, eidx, Wm1, bm1, Wm2, bm2, Wu1, bu1, Wu2, bu2,
                       gamma_, beta_, outp);
  }
}

// Round 8
// 44.536 us; speedup vs baseline: 1.1052x; 1.1052x over previous
//
#include <hip/hip_runtime.h>
#include <hip/hip_bf16.h>

// Fused MPNN layer, B=256, N=81, H=128, E=1620 — MFMA bf16, half-split blocks.
//   P = X @ Wm1[:H],  Q' = X @ Wm1[H:] + bm1
//   Hsum[t] = sum_{e: tgt=t} relu(P[src_e] + Q'[t])
//   Folded:  agg@Wu1b = (Hsum@Wc)*inv_deg + 1[deg>0]*bc,  Wc=Wm2@Wu1b, bc=bm2@Wu1b
//   h2 = relu(X@Wu1t + (Hsum@Wc)*inv + s*bc + bu1)
//   x  = X + h2 @ Wu2 + bu2 ;  out = LayerNorm(x)*gamma + beta
// Setup (grid 13 x 1024): pack weights, ballot-CSR, Wc/bc  (as r6).
// Main  (grid 512 = batch x half, 512 thr = 8 waves, 71 KB LDS, 2 blocks/CU):
//   each half-block computes P for all 96 rows, everything else for its
//   48/33-row half. Two barrier domains per CU overlap each other's stalls.

#define NN 81
#define HH 128
#define EE 1620
#define NCHK 26                         // ceil(EE/64)
#define MPAD 96
#define WB_BYTES 196608                 // 6 * 16384 ushorts (slot4 unused)
#define OFFS_OFF (WB_BYTES)             // int offs[82]
#define CSR_OFF  (OFFS_OFF + 82 * 4)    // int csr[1620]
#define BC_OFF   (CSR_OFF + EE * 4)     // float bc[128]
#define WS_NEED  (BC_OFF + HH * 4)

// main-kernel LDS arena offsets (bytes)
#define XB_OFF   0                      // bf16 swz [96][128]   24576
#define BP_OFF   24576                  // bf16 swz [96][128]   24576  (P -> h2; aliased by xout)
#define BQ_OFF   49152                  // bf16 swz [48][128]   12288  (Q' -> Hsum, local rows)
#define CSRL_OFF 61440                  // int[1620]             6480
#define OFFH_OFF 67920                  // int[52]                208
#define BIAS_OFF 68128                  // float[6][128]         3072
#define L_BYTES  71232

typedef __attribute__((ext_vector_type(8))) short bf16x8;
typedef __attribute__((ext_vector_type(8))) unsigned short ushort8v;
typedef __attribute__((ext_vector_type(4))) float f32x4;

__device__ __forceinline__ unsigned short f2b(float f) {
  union { float f; unsigned u; } v; v.f = f;
  unsigned r = v.u + 0x7fffu + ((v.u >> 16) & 1u);
  return (unsigned short)(r >> 16);
}
__device__ __forceinline__ float b2f(unsigned short h) {
  union { unsigned u; float f; } v; v.u = ((unsigned)h) << 16;
  return v.f;
}
__device__ __forceinline__ unsigned f2b2(float x, float y) {  // packed RNE pair
  float2 f; f.x = x; f.y = y;
  union { __hip_bfloat162 h; unsigned u; } v;
  v.h = __float22bfloat162_rn(f);
  return v.u;
}
__device__ __forceinline__ unsigned swzu(int r, int laneb) {
  return ((unsigned)(r * 256 + laneb)) ^ ((unsigned)((r & 7) << 4));
}

// ---------------- setup kernel (unchanged from r6) ---------------------------
__global__ __launch_bounds__(1024)
void setup_kernel(const float* __restrict__ Wm1, const float* __restrict__ Wm2,
                  const float* __restrict__ Wu1, const float* __restrict__ Wu2,
                  const float* __restrict__ bm2, const int* __restrict__ eidx,
                  char* __restrict__ ws) {
  __shared__ __align__(16) char arena[81920];
  const int tid = threadIdx.x;

  if (blockIdx.x < 8) {
    const int gid = blockIdx.x * 1024 + tid;
    const int lane = gid & 63;
    const int t = gid >> 6;
    const int ks = t & 3, nt = (t >> 2) & 7, mat = t >> 5;
    const float* src;
    int slot;
    if (mat == 0)      { src = Wm1;           slot = 0; }
    else if (mat == 1) { src = Wm1 + HH * HH; slot = 1; }
    else if (mat == 2) { src = Wu1;           slot = 3; }
    else               { src = Wu2;           slot = 5; }
    const int c = nt * 16 + (lane & 15);
    const int k0 = ks * 32 + (lane >> 4) * 8;
    bf16x8 pv;
#pragma unroll
    for (int j = 0; j < 8; ++j) pv[j] = (short)f2b(src[(k0 + j) * HH + c]);
    *(bf16x8*)((unsigned short*)ws + (size_t)slot * 16384 + (((nt * 4 + ks) * 64) + lane) * 8) = pv;
    return;
  }

  if (blockIdx.x == 8) {
    int* srcE  = (int*)arena;            // EE
    int* tgtE  = srcE + EE;              // EE
    int* rankS = tgtE + EE;              // EE
    int* cntC  = rankS + EE;             // NCHK*NN
    int* tot   = cntC + NCHK * NN;       // NN
    int* scanS = tot + NN;               // 128
    int* wsumS = scanS + 128;            // 2
    int* offsS = wsumS + 2;              // NN+1
    for (int i = tid; i < NCHK * NN; i += 1024) cntC[i] = 0;
    for (int i = tid; i < 2 * EE; i += 1024) srcE[i] = eidx[i];
    __syncthreads();
    const int lane = tid & 63, wv = tid >> 6;
    for (int c = wv; c < NCHK; c += 16) {
      const int e = c * 64 + lane;
      const bool ok = (e < EE);
      const int t = ok ? tgtE[e] : -1;
      unsigned long long mymask = 0;
#pragma unroll
      for (int i = 0; i < 64; ++i) {
        const int ti = __shfl(t, i);
        const unsigned long long bal = __ballot(t == ti);
        if (i == lane) mymask = bal;
      }
      if (ok) {
        const int rank = __popcll(mymask & ((1ull << lane) - 1ull));
        rankS[e] = rank;
        if (rank == 0) cntC[c * NN + t] = __popcll(mymask);
      }
    }
    __syncthreads();
    if (tid < NN) {
      int s = 0;
#pragma unroll
      for (int c = 0; c < NCHK; ++c) s += cntC[c * NN + tid];
      tot[tid] = s;
    }
    __syncthreads();
    if (tid < 128) {
      const int l = tid & 63, w = tid >> 6;
      int inc = (tid < NN) ? tot[tid] : 0;
#pragma unroll
      for (int d = 1; d < 64; d <<= 1) {
        int u = __shfl_up(inc, d);
        if (l >= d) inc += u;
      }
      scanS[tid] = inc;
      if (l == 63) wsumS[w] = inc;
    }
    __syncthreads();
    if (tid < 128) {
      const int w = tid >> 6;
      const int inc = scanS[tid] + (w ? wsumS[0] : 0);
      if (tid < NN) offsS[tid] = inc - tot[tid];
      if (tid == NN - 1) offsS[NN] = inc;
    }
    __syncthreads();
    if (tid < NN) {
      int run = offsS[tid];
#pragma unroll
      for (int c = 0; c < NCHK; ++c) {
        const int tmp = cntC[c * NN + tid];
        cntC[c * NN + tid] = run;
        run += tmp;
      }
    }
    __syncthreads();
    int* wofs = (int*)(ws + OFFS_OFF);
    int* wcsr = (int*)(ws + CSR_OFF);
    for (int i = tid; i <= NN; i += 1024) wofs[i] = offsS[i];
    for (int e = tid; e < EE; e += 1024) {
      const int t = tgtE[e];
      wcsr[cntC[(e >> 6) * NN + t] + rankS[e]] = srcE[e];
    }
    return;
  }

  // blocks 9-12: Wc = Wm2 @ Wu1b, rows [32*bs,32*bs+32); pack slot 2; bs0: bc
  {
    const int bs = blockIdx.x - 9;
    float* WuL = (float*)arena;
    float* WmL = WuL + HH * HH;
    const float* Wu1b = Wu1 + HH * HH;
    float4* WuL4 = (float4*)WuL;
    const float4* src4 = (const float4*)Wu1b;
    for (int i = tid; i < HH * HH / 4; i += 1024) WuL4[i] = src4[i];
    const float4* wm4 = (const float4*)(Wm2 + bs * 32 * HH);
    float4* WmL4 = (float4*)WmL;
    if (tid < 32 * HH / 4) WmL4[tid] = wm4[tid];
    __syncthreads();
    const int kk = tid >> 5;
    const int k  = bs * 32 + kk;
    const int cg = tid & 31;
    f32x4 acc = (f32x4)0.f;
    for (int j = 0; j < HH; ++j) {
      const float a = WmL[kk * HH + j];
      const float4 w = WuL4[j * 32 + cg];
      acc[0] += a * w.x; acc[1] += a * w.y; acc[2] += a * w.z; acc[3] += a * w.w;
    }
    unsigned short* dst = (unsigned short*)ws;
#pragma unroll
    for (int q = 0; q < 4; ++q) {
      const int c = cg * 4 + q;
      const int nt = c >> 4;
      const int l = (((k & 31) >> 3) << 4) | (c & 15);
      dst[(size_t)2 * 16384 + (((nt * 4 + bs) * 64) + l) * 8 + (k & 7)] = f2b(acc[q]);
    }
    if (bs == 0 && tid < HH) {
      float s = 0.f;
      for (int j = 0; j < HH; ++j) s += bm2[j] * WuL[j * HH + tid];
      ((float*)(ws + BC_OFF))[tid] = s;
    }
  }
}

// ---------------- MFMA helpers ----------------------------------------------
__device__ __forceinline__ void loadB(const unsigned short* Wp, int nt0, int lane,
                                      bf16x8 (&Bf)[4]) {
#pragma unroll
  for (int ks = 0; ks < 4; ++ks)
    Bf[ks] = *(const bf16x8*)(Wp + ((nt0 * 4 + ks) * 64 + lane) * 8);
}

template <int MT>
__device__ __forceinline__ void gemmNx1(const char* Ab, int rowbase,
                                        const bf16x8 (&Bf)[4], int lane,
                                        f32x4 (&acc)[MT]) {
  const int rl = lane & 15;
  const int kb = (lane >> 4) * 16;
  const unsigned swz = (unsigned)((rl & 7) << 4);
#pragma unroll
  for (int ks = 0; ks < 4; ++ks)
#pragma unroll
    for (int mm = 0; mm < MT; ++mm) {
      const int r = rowbase + mm * 16 + rl;
      const unsigned byte = (unsigned)(r * 256) + (((unsigned)(ks * 64 + kb)) ^ swz);
      bf16x8 a = *(const bf16x8*)(Ab + byte);
      acc[mm] = __builtin_amdgcn_mfma_f32_16x16x32_bf16(a, Bf[ks], acc[mm], 0, 0, 0);
    }
}

// ---------------- main kernel: one half-batch per block -----------------------
__global__ __launch_bounds__(512, 4)
void mpnn_half_kernel(const float* __restrict__ node,
                      const float* __restrict__ bm1,
                      const float* __restrict__ bu1, const float* __restrict__ bu2,
                      const float* __restrict__ gamma_, const float* __restrict__ beta_,
                      const char* __restrict__ ws,
                      float* __restrict__ out) {
  __shared__ __align__(16) char L[L_BYTES];
  char* Xb   = L + XB_OFF;
  char* bufP = L + BP_OFF;
  char* bufQ = L + BQ_OFF;
  int*  csrL = (int*)(L + CSRL_OFF);
  int*  offsH= (int*)(L + OFFH_OFF);
  float (*bias)[HH] = (float(*)[HH])(L + BIAS_OFF);
  float* xout = (float*)(L + BP_OFF);          // alias bufP (dead by then)

  const int tid  = threadIdx.x;
  const int lane = tid & 63;
  const int wave = tid >> 6;                   // 0..7
  const int b    = blockIdx.x & 255;
  const int half = blockIdx.x >> 8;            // same XCD for both halves of b
  const int t0   = half * 48;
  const int tcnt = half ? (NN - 48) : 48;      // 33 : 48
  const int rbase = half * 48;                 // global row base of own half

  const unsigned short* wpk = (const unsigned short*)ws;
  const int* wofs = (const int*)(ws + OFFS_OFF);
  const int* wcsr = (const int*)(ws + CSR_OFF);
  const float* wbc = (const float*)(ws + BC_OFF);

  const int nt0 = wave;                        // 8 waves = 8 N-tiles
  const int erow = (lane >> 4) * 4;
  const int ecol = lane & 15;

  // ---- GEMM A B-frag preload (global; independent of staging) ----
  bf16x8 BA0[4], BA1[4];
  loadB(wpk, nt0, lane, BA0);
  loadB(wpk + 16384, nt0, lane, BA1);

  // ---- stage: full X -> Xb (swizzled bf16); csr slice; offs; biases ----
  {
    const float4* nf4 = (const float4*)(node + (size_t)b * NN * HH);
    float4 v[5];
#pragma unroll
    for (int k = 0; k < 5; ++k) v[k] = nf4[tid + k * 512];
    const bool tail = (tid < 2592 - 2560);     // 2592 float4 total
    float4 v5;
    if (tail) v5 = nf4[tid + 2560];
#pragma unroll
    for (int k = 0; k < 5; ++k) {
      const int i = tid + k * 512;
      const int r = i >> 5, c = (i & 31) * 4;
      uint2 pv; pv.x = f2b2(v[k].x, v[k].y); pv.y = f2b2(v[k].z, v[k].w);
      *(uint2*)(Xb + swzu(r, c * 2)) = pv;
    }
    if (tail) {
      const int i = tid + 2560;
      const int r = i >> 5, c = (i & 31) * 4;
      uint2 pv; pv.x = f2b2(v5.x, v5.y); pv.y = f2b2(v5.z, v5.w);
      *(uint2*)(Xb + swzu(r, c * 2)) = pv;
    }
    if (tid < (MPAD - NN) * 16) {              // zero pad rows 81..95
      const int r = NN + tid / 16, m = tid % 16;
      ushort8v z = {0,0,0,0,0,0,0,0};
      *(ushort8v*)(Xb + swzu(r, m * 16)) = z;
    }
    const int e0 = wofs[t0];
    if (tid <= tcnt) offsH[tid] = wofs[t0 + tid] - e0;
    const int ecnt = wofs[t0 + tcnt] - e0;
    for (int i = tid; i < ecnt; i += 512) csrL[i] = wcsr[e0 + i];
    if (tid < HH) {
      bias[0][tid] = bm1[tid];  bias[1][tid] = wbc[tid];
      bias[2][tid] = bu1[tid];  bias[3][tid] = bu2[tid];
      bias[4][tid] = gamma_[tid]; bias[5][tid] = beta_[tid];
    }
  }
  __syncthreads();

  // ---- GEMM A: P(all 96 rows) -> bufP ; Q'(own half) + bm1 -> bufQ local ----
  {
    f32x4 accP[6], accQ[3];
#pragma unroll
    for (int mm = 0; mm < 6; ++mm) accP[mm] = (f32x4)0.f;
#pragma unroll
    for (int mm = 0; mm < 3; ++mm) accQ[mm] = (f32x4)0.f;
    gemmNx1<6>(Xb, 0, BA0, lane, accP);
    gemmNx1<3>(Xb, rbase, BA1, lane, accQ);
    const int C = nt0 * 16 + ecol;
#pragma unroll
    for (int mm = 0; mm < 6; ++mm)
#pragma unroll
      for (int rg = 0; rg < 4; ++rg) {
        const int R = mm * 16 + erow + rg;     // pad rows: computed from zero Xb, harmless
        *(unsigned short*)(bufP + swzu(R, C * 2)) = f2b(accP[mm][rg]);
      }
#pragma unroll
    for (int mm = 0; mm < 3; ++mm)
#pragma unroll
      for (int rg = 0; rg < 4; ++rg) {
        const int lr = mm * 16 + erow + rg;    // local row 0..47
        const bool ok = (rbase + lr < NN);
        *(unsigned short*)(bufQ + swzu(lr, C * 2)) =
            ok ? f2b(accQ[mm][rg] + bias[0][C]) : (unsigned short)0;
      }
  }
  __syncthreads();

  // ---- edge aggregation (x4 unrolled, r6 form): Hsum -> bufQ local ----
  {
    const int lb = lane * 4;
    for (int tl = wave; tl < tcnt; tl += 8) {
      const unsigned qbyte = swzu(tl, lb);
      const unsigned pq = *(const unsigned*)(bufQ + qbyte);
      const float q0 = b2f((unsigned short)(pq & 0xffff));
      const float q1 = b2f((unsigned short)(pq >> 16));
      float h0 = 0.f, h1 = 0.f, g0 = 0.f, g1 = 0.f;
      int e = offsH[tl];
      const int o1 = offsH[tl + 1];
      for (; e + 4 <= o1; e += 4) {
        const int s0 = csrL[e], s1 = csrL[e + 1], s2 = csrL[e + 2], s3 = csrL[e + 3];
        const unsigned p0 = *(const unsigned*)(bufP + swzu(s0, lb));
        const unsigned p1 = *(const unsigned*)(bufP + swzu(s1, lb));
        const unsigned p2 = *(const unsigned*)(bufP + swzu(s2, lb));
        const unsigned p3 = *(const unsigned*)(bufP + swzu(s3, lb));
        h0 += fmaxf(b2f((unsigned short)(p0 & 0xffff)) + q0, 0.f);
        h1 += fmaxf(b2f((unsigned short)(p0 >> 16))    + q1, 0.f);
        g0 += fmaxf(b2f((unsigned short)(p1 & 0xffff)) + q0, 0.f);
        g1 += fmaxf(b2f((unsigned short)(p1 >> 16))    + q1, 0.f);
        h0 += fmaxf(b2f((unsigned short)(p2 & 0xffff)) + q0, 0.f);
        h1 += fmaxf(b2f((unsigned short)(p2 >> 16))    + q1, 0.f);
        g0 += fmaxf(b2f((unsigned short)(p3 & 0xffff)) + q0, 0.f);
        g1 += fmaxf(b2f((unsigned short)(p3 >> 16))    + q1, 0.f);
      }
      for (; e < o1; ++e) {
        const int s = csrL[e];
        const unsigned pp = *(const unsigned*)(bufP + swzu(s, lb));
        h0 += fmaxf(b2f((unsigned short)(pp & 0xffff)) + q0, 0.f);
        h1 += fmaxf(b2f((unsigned short)(pp >> 16))    + q1, 0.f);
      }
      h0 += g0; h1 += g1;
      const unsigned hv = (unsigned)f2b(h0) | ((unsigned)f2b(h1) << 16);
      *(unsigned*)(bufQ + qbyte) = hv;
    }
  }
  __syncthreads();

  // ---- GEMM BC: T = Hsum@Wc ; U = Xb@Wu1t ;  h2 -> bufP LOCAL rows ----
  {
    bf16x8 BW[4], BU[4];
    loadB(wpk + 2 * 16384, nt0, lane, BW);
    loadB(wpk + 3 * 16384, nt0, lane, BU);
    f32x4 accT[3], accU[3];
#pragma unroll
    for (int mm = 0; mm < 3; ++mm) { accT[mm] = (f32x4)0.f; accU[mm] = (f32x4)0.f; }
    gemmNx1<3>(bufQ, 0, BW, lane, accT);       // local rows
    gemmNx1<3>(Xb, rbase, BU, lane, accU);     // global rows
    const int C = nt0 * 16 + ecol;
#pragma unroll
    for (int mm = 0; mm < 3; ++mm)
#pragma unroll
      for (int rg = 0; rg < 4; ++rg) {
        const int lr = mm * 16 + erow + rg;
        float v = 0.f;
        if (lr < tcnt) {
          const int dg = offsH[lr + 1] - offsH[lr];
          const float inv = (dg > 0) ? 1.f / (float)dg : 1.f;
          const float sf  = (dg > 0) ? 1.f : 0.f;
          v = fmaxf(accU[mm][rg] + accT[mm][rg] * inv + sf * bias[1][C] + bias[2][C], 0.f);
        }
        *(unsigned short*)(bufP + swzu(lr, C * 2)) = f2b(v);
      }
  }
  __syncthreads();

  // ---- GEMM D: x = X + h2@Wu2 + bu2 ; residual re-read from global (L2) ----
  {
    bf16x8 BD[4];
    loadB(wpk + 5 * 16384, nt0, lane, BD);
    f32x4 accD[3];
#pragma unroll
    for (int mm = 0; mm < 3; ++mm) accD[mm] = (f32x4)0.f;
    gemmNx1<3>(bufP, 0, BD, lane, accD);       // h2, local rows
    __syncthreads();                           // all bufP reads done before xout alias write
    const float* nodeB = node + (size_t)b * NN * HH;
    const int C = nt0 * 16 + ecol;
#pragma unroll
    for (int mm = 0; mm < 3; ++mm)
#pragma unroll
      for (int rg = 0; rg < 4; ++rg) {
        const int lr = mm * 16 + erow + rg;
        if (lr < tcnt) {
          const int R = t0 + lr;
          const float resid = nodeB[R * HH + C];
          xout[lr * HH + C] = resid + accD[mm][rg] + bias[3][C];
        }
      }
  }
  __syncthreads();

  // ---- LayerNorm on xout (local rows) + store ----
  {
    float x0[6], x1[6], mu[6], rstd[6];
#pragma unroll
    for (int k = 0; k < 6; ++k) {
      const int lr = wave + 8 * k;
      const int rr = (lr < tcnt) ? lr : 0;
      x0[k] = xout[rr * HH + lane]; x1[k] = xout[rr * HH + lane + 64];
    }
#pragma unroll
    for (int k = 0; k < 6; ++k) {
      float s = x0[k] + x1[k];
#pragma unroll
      for (int off = 32; off; off >>= 1) s += __shfl_xor(s, off);
      mu[k] = s * (1.f / 128.f);
    }
#pragma unroll
    for (int k = 0; k < 6; ++k) {
      const float d0 = x0[k] - mu[k], d1 = x1[k] - mu[k];
      float v = d0 * d0 + d1 * d1;
#pragma unroll
      for (int off = 32; off; off >>= 1) v += __shfl_xor(v, off);
      rstd[k] = rsqrtf(v * (1.f / 128.f) + 1e-5f);
    }
#pragma unroll
    for (int k = 0; k < 6; ++k) {
      const int lr = wave + 8 * k;
      if (lr < tcnt) {
        const float d0 = x0[k] - mu[k], d1 = x1[k] - mu[k];
        const size_t o = ((size_t)b * NN + (t0 + lr)) * HH;
        out[o + lane]      = d0 * rstd[k] * bias[4][lane]      + bias[5][lane];
        out[o + lane + 64] = d1 * rstd[k] * bias[4][lane + 64] + bias[5][lane + 64];
      }
    }
  }
}

// ================= fp32 fallback (known-good, used only if ws too small) =====
__device__ __forceinline__ void gemm_acc_f32(const float (*A)[HH], const float* __restrict__ Wg,
                                             int c, int row0, int nr, float (&acc)[41]) {
  float w[8];
#pragma unroll
  for (int j = 0; j < 8; ++j) w[j] = Wg[j * HH + c];
  for (int k0 = 0; k0 < HH; k0 += 8) {
    float wn[8];
    if (k0 + 8 < HH) {
#pragma unroll
      for (int j = 0; j < 8; ++j) wn[j] = Wg[(k0 + 8 + j) * HH + c];
    }
#pragma unroll
    for (int i = 0; i < 41; ++i) {
      if (i < nr) {
        const float4 a0 = *(const float4*)&A[row0 + i][k0];
        const float4 a1 = *(const float4*)&A[row0 + i][k0 + 4];
        acc[i] += a0.x * w[0] + a0.y * w[1] + a0.z * w[2] + a0.w * w[3]
                + a1.x * w[4] + a1.y * w[5] + a1.z * w[6] + a1.w * w[7];
      }
    }
#pragma unroll
    for (int j = 0; j < 8; ++j) w[j] = wn[j];
  }
}

__global__ __launch_bounds__(256, 1)
void mpnn_fused_kernel(const float* __restrict__ node, const int* __restrict__ eidx,
                       const float* __restrict__ Wm1, const float* __restrict__ bm1,
                       const float* __restrict__ Wm2, const float* __restrict__ bm2,
                       const float* __restrict__ Wu1, const float* __restrict__ bu1,
                       const float* __restrict__ Wu2, const float* __restrict__ bu2,
                       const float* __restrict__ gamma_, const float* __restrict__ beta_,
                       float* __restrict__ out) {
  __shared__ float X[NN][HH];
  __shared__ float Pb[NN][HH];
  __shared__ float Qb[NN][HH];
  __shared__ int   edg[2 * EE];
  __shared__ int   csr[EE];
  __shared__ int   offs[NN + 1];
  __shared__ int   cnt3[3][NN];
  __shared__ int   base3[3][NN];
  __shared__ float biases[6][HH];

  const int tid  = threadIdx.x;
  const int lane = tid & 63;
  const int wave = tid >> 6;
  const int b    = blockIdx.x;

  {
    const float4* nf4 = (const float4*)(node + (size_t)b * NN * HH);
    float4* X4 = (float4*)&X[0][0];
    for (int i = tid; i < NN * HH / 4; i += 256) X4[i] = nf4[i];
    for (int i = tid; i < 2 * EE; i += 256) edg[i] = eidx[i];
    if (tid < HH) {
      biases[0][tid] = bm1[tid]; biases[1][tid] = bm2[tid];
      biases[2][tid] = bu1[tid]; biases[3][tid] = bu2[tid];
      biases[4][tid] = gamma_[tid]; biases[5][tid] = beta_[tid];
    }
  }
  __syncthreads();
  if (tid < 3 * NN) {
    const int t = tid % NN, ch = tid / NN;
    const int e0 = ch * 540, e1 = e0 + 540;
    int cnt = 0;
    for (int e = e0; e < e1; ++e) cnt += (edg[EE + e] == t);
    cnt3[ch][t] = cnt;
  }
  __syncthreads();
  if (tid == 0) {
    int run = 0;
    for (int t = 0; t < NN; ++t) {
      offs[t] = run;
      base3[0][t] = run;
      base3[1][t] = base3[0][t] + cnt3[0][t];
      base3[2][t] = base3[1][t] + cnt3[1][t];
      run = base3[2][t] + cnt3[2][t];
    }
    offs[NN] = run;
  }
  __syncthreads();
  if (tid < 3 * NN) {
    const int t = tid % NN, ch = tid / NN;
    const int e0 = ch * 540, e1 = e0 + 540;
    int pos = base3[ch][t];
    for (int e = e0; e < e1; ++e)
      if (edg[EE + e] == t) csr[pos++] = edg[e];
  }
  __syncthreads();

  const int c    = ((wave & 1) << 6) | lane;
  const int row0 = (wave >> 1) ? 41 : 0;
  const int nr   = (wave >> 1) ? 40 : 41;

  {
    float acc[41];
#pragma unroll
    for (int i = 0; i < 41; ++i) acc[i] = 0.f;
    gemm_acc_f32(X, Wm1, c, row0, nr, acc);
#pragma unroll
    for (int i = 0; i < 41; ++i) if (i < nr) Pb[row0 + i][c] = acc[i];
  }
  {
    float acc[41];
#pragma unroll
    for (int i = 0; i < 41; ++i) acc[i] = 0.f;
    gemm_acc_f32(X, Wm1 + HH * HH, c, row0, nr, acc);
#pragma unroll
    for (int i = 0; i < 41; ++i) if (i < nr) Qb[row0 + i][c] = acc[i];
  }
  __syncthreads();

  for (int t = wave; t < NN; t += 4) {
    const int o0 = offs[t], o1 = offs[t + 1];
    const float q0 = Qb[t][lane]      + biases[0][lane];
    const float q1 = Qb[t][lane + 64] + biases[0][lane + 64];
    float h0 = 0.f, h1 = 0.f;
    for (int e = o0; e < o1; ++e) {
      const int s = csr[e];
      h0 += fmaxf(Pb[s][lane]      + q0, 0.f);
      h1 += fmaxf(Pb[s][lane + 64] + q1, 0.f);
    }
    Qb[t][lane]      = h0;
    Qb[t][lane + 64] = h1;
  }
  __syncthreads();

  {
    float acc[41];
#pragma unroll
    for (int i = 0; i < 41; ++i) acc[i] = 0.f;
    gemm_acc_f32(Qb, Wm2, c, row0, nr, acc);
#pragma unroll
    for (int i = 0; i < 41; ++i) if (i < nr) {
      const int r = row0 + i;
      const float d = (float)(offs[r + 1] - offs[r]);
      Pb[r][c] = (acc[i] + d * biases[1][c]) * (1.f / fmaxf(d, 1.f));
    }
  }
  __syncthreads();

  {
    float acc[41];
#pragma unroll
    for (int i = 0; i < 41; ++i) acc[i] = 0.f;
    gemm_acc_f32(X,  Wu1,           c, row0, nr, acc);
    gemm_acc_f32(Pb, Wu1 + HH * HH, c, row0, nr, acc);
#pragma unroll
    for (int i = 0; i < 41; ++i) if (i < nr)
      Qb[row0 + i][c] = fmaxf(acc[i] + biases[2][c], 0.f);
  }
  __syncthreads();

  {
    float acc[41];
#pragma unroll
    for (int i = 0; i < 41; ++i) acc[i] = 0.f;
    gemm_acc_f32(Qb, Wu2, c, row0, nr, acc);
#pragma unroll
    for (int i = 0; i < 41; ++i) if (i < nr) {
      const int r = row0 + i;
      X[r][c] = X[r][c] + acc[i] + biases[3][c];
    }
  }
  __syncthreads();

  for (int r = wave; r < NN; r += 4) {
    const float x0 = X[r][lane], x1 = X[r][lane + 64];
    float s = x0 + x1;
#pragma unroll
    for (int off = 32; off; off >>= 1) s += __shfl_xor(s, off);
    const float mu = s * (1.f / 128.f);
    const float d0 = x0 - mu, d1 = x1 - mu;
    float v = d0 * d0 + d1 * d1;
#pragma unroll
    for (int off = 32; off; off >>= 1) v += __shfl_xor(v, off);
    const float rstd = rsqrtf(v * (1.f / 128.f) + 1e-5f);
    const size_t o = ((size_t)b * NN + r) * HH;
    out[o + lane]      = d0 * rstd * biases[4][lane]      + biases[5][lane];
    out[o + lane + 64] = d1 * rstd * biases[4][lane + 64] + biases[5][lane + 64];
  }
}

extern "C" void kernel_launch(void* const* d_in, const int* in_sizes, int n_in,
                              void* d_out, int out_size, void* d_ws, size_t ws_size,
                              hipStream_t stream) {
  (void)in_sizes; (void)n_in; (void)out_size;
  const float* node  = (const float*)d_in[0];
  const int*   eidx  = (const int*)  d_in[1];
  const float* Wm1   = (const float*)d_in[2];
  const float* bm1   = (const float*)d_in[3];
  const float* Wm2   = (const float*)d_in[4];
  const float* bm2   = (const float*)d_in[5];
  const float* Wu1   = (const float*)d_in[6];
  const float* bu1   = (const float*)d_in[7];
  const float* Wu2   = (const float*)d_in[8];
  const float* bu2   = (const float*)d_in[9];
  const float* gamma_= (const float*)d_in[10];
  const float* beta_ = (const float*)d_in[11];
  float* outp = (float*)d_out;

  if (ws_size >= (size_t)WS_NEED) {
    char* ws = (char*)d_ws;
    hipLaunchKernelGGL(setup_kernel, dim3(13), dim3(1024), 0, stream,
                       Wm1, Wm2, Wu1, Wu2, bm2, eidx, ws);
    hipLaunchKernelGGL(mpnn_half_kernel, dim3(512), dim3(512), 0, stream,
                       node, bm1, bu1, bu2, gamma_, beta_, ws, outp);
  } else {
    hipLaunchKernelGGL(mpnn_fused_kernel, dim3(256), dim3(256), 0, stream,
                       node, eidx, Wm1, bm1, Wm2, bm2, Wu1, bu1, Wu2, bu2,
                       gamma_, beta_, outp);
  }
}